// Round 5
// baseline (169.799 us; speedup 1.0000x reference)
//
#include <hip/hip_runtime.h>

// FeatLUT: out[f] = quantize( mean_p( msb[idx_m(p)][f] + lsb[idx_l(p)][f] ) )
// idx = 16*(289*c0 + 17*c1 + c2)  -> only 17^3 = 4913 distinct rows used.
// Strategy: per-block LDS histogram of the 4913 small indices, per-block dot
// against compacted tables -> NON-ATOMIC per-block partials, tree-reduce.
//
// Session mines (do not re-trip):
//  - 40960 same-cacheline global atomics serialized = 417us (orig session).
//  - __launch_bounds__ min-waves squeezes VGPR (52->28), serializes load
//    bundles: VALUBusy 6%, 3x slower (R2).
//  - Fused last-block finalize with __threadfence(): agent-scope fence on
//    8-XCD gfx950 = bulk L2 writeback/invalidate per block -> nukes L2 under
//    concurrent streamers; slow even with warm L3 (R2/R3/R4, 3-5x).
//
// R5 result: packed hist (20KB LDS) verified at 157us, but occupancy stayed
// 37% because the GRID (1024 = 4 blocks/CU) became the residency cap, not
// LDS. Measured consumption 1.88 TB/s == 16 waves/CU in-flight-bytes model.
// R6 single change: grid 1024 -> 2048 (8 blocks/CU, 32 waves/CU).

#define NBINS 4913            // 17^3
#define NPIX  (2048 * 2048)   // 4194304
#define G4    (NPIX / 4)      // 1048576 float4 groups per channel plane
#define NFEAT 20

// ---------------------------------------------------------------------------
// Kernel 0: compact the used LUT rows (row 16*j, j in [0,4913)) into dense
// 20-byte rows stored as 5 dwords each. Handles both harness layouts for the
// int8 tables: (a) raw int8 bytes, (b) widened to int32. Detection: random
// packed bytes essentially never stay in [-32,32) 64x in a row.
// ---------------------------------------------------------------------------
__global__ __launch_bounds__(256) void compact_k(const int* __restrict__ msb,
                                                 const int* __restrict__ lsb,
                                                 int* __restrict__ cm,
                                                 int* __restrict__ cl) {
    int ok = 1;
    for (int i = 0; i < 64; ++i) {
        int v = msb[i];
        ok &= (v >= -32 && v < 32);
    }
    const bool is_int32 = (ok != 0);

    const int total = NBINS * 5;  // dwords per compact table
    int t = blockIdx.x * 256 + threadIdx.x;
    const int stride = gridDim.x * 256;
    for (; t < total; t += stride) {
        int j = t / 5;
        int k = t - j * 5;
        int wm, wl;
        if (is_int32) {
            // source: int per element; row 16j starts at element 16j*20 = 320j
            const int* rm = msb + j * 320 + k * 4;
            const int* rl = lsb + j * 320 + k * 4;
            unsigned um = (unsigned)(rm[0] & 0xff) | ((unsigned)(rm[1] & 0xff) << 8) |
                          ((unsigned)(rm[2] & 0xff) << 16) | ((unsigned)(rm[3] & 0xff) << 24);
            unsigned ul = (unsigned)(rl[0] & 0xff) | ((unsigned)(rl[1] & 0xff) << 8) |
                          ((unsigned)(rl[2] & 0xff) << 16) | ((unsigned)(rl[3] & 0xff) << 24);
            wm = (int)um;
            wl = (int)ul;
        } else {
            // source: raw int8; row 16j at byte 320j -> dword 80j, 5 dwords/row
            wm = msb[j * 80 + k];
            wl = lsb[j * 80 + k];
        }
        cm[t] = wm;
        cl[t] = wl;
    }
}

// ---------------------------------------------------------------------------
// Kernel 1: main. gridDim.x x 256 threads.
//  - packed LDS histogram (4913 ints, msb lo16 / lsb hi16; per-block count
//    per table <= 4096 < 2^16, no cross-field carry)
//  - float4 streaming of x_in / x_s (grid-stride, exact divisor, no tail)
//  - per-block dot against compact tables, wave shuffle reduce, LDS combine,
//    one NON-ATOMIC 20-int partial row per block.
// ---------------------------------------------------------------------------
__global__ __launch_bounds__(256) void feat_main(const float* __restrict__ xin,
                                                 const float* __restrict__ xs,
                                                 const int* __restrict__ cm,
                                                 const int* __restrict__ cl,
                                                 int* __restrict__ partial) {
    __shared__ int hist[NBINS];   // 19652 B -> 8 blocks/CU
    __shared__ int wsum[4][NFEAT];
    for (int i = threadIdx.x; i < NBINS; i += 256) hist[i] = 0;
    __syncthreads();

    const float4* a = (const float4*)xin;
    const float4* b = (const float4*)xs;
    const int nt = gridDim.x * 256;
    for (int g = blockIdx.x * 256 + threadIdx.x; g < G4; g += nt) {
        float4 a0 = a[g], a1 = a[g + G4], a2 = a[g + 2 * G4];
        float4 b0 = b[g], b1 = b[g + G4], b2 = b[g + 2 * G4];

        int m0 = (int)fmaf(a0.x, 289.0f, fmaf(a1.x, 17.0f, a2.x));
        int m1 = (int)fmaf(a0.y, 289.0f, fmaf(a1.y, 17.0f, a2.y));
        int m2 = (int)fmaf(a0.z, 289.0f, fmaf(a1.z, 17.0f, a2.z));
        int m3 = (int)fmaf(a0.w, 289.0f, fmaf(a1.w, 17.0f, a2.w));
        int s0 = (int)fmaf(b0.x, 289.0f, fmaf(b1.x, 17.0f, b2.x));
        int s1 = (int)fmaf(b0.y, 289.0f, fmaf(b1.y, 17.0f, b2.y));
        int s2 = (int)fmaf(b0.z, 289.0f, fmaf(b1.z, 17.0f, b2.z));
        int s3 = (int)fmaf(b0.w, 289.0f, fmaf(b1.w, 17.0f, b2.w));

        atomicAdd(&hist[m0], 1);
        atomicAdd(&hist[m1], 1);
        atomicAdd(&hist[m2], 1);
        atomicAdd(&hist[m3], 1);
        atomicAdd(&hist[s0], 1 << 16);
        atomicAdd(&hist[s1], 1 << 16);
        atomicAdd(&hist[s2], 1 << 16);
        atomicAdd(&hist[s3], 1 << 16);
    }
    __syncthreads();

    // per-block dot product: acc[f] += hm[j]*msb_row[j][f] + hl[j]*lsb_row[j][f]
    int acc[NFEAT];
#pragma unroll
    for (int f = 0; f < NFEAT; ++f) acc[f] = 0;

    for (int j = threadIdx.x; j < NBINS; j += 256) {
        int h = hist[j];
        int hm = h & 0xffff;
        int hl = (int)((unsigned)h >> 16);
        if (hm) {
            const int* r = cm + j * 5;
#pragma unroll
            for (int k = 0; k < 5; ++k) {
                int w = r[k];
                acc[4 * k + 0] += hm * ((w << 24) >> 24);
                acc[4 * k + 1] += hm * ((w << 16) >> 24);
                acc[4 * k + 2] += hm * ((w << 8) >> 24);
                acc[4 * k + 3] += hm * (w >> 24);
            }
        }
        if (hl) {
            const int* r = cl + j * 5;
#pragma unroll
            for (int k = 0; k < 5; ++k) {
                int w = r[k];
                acc[4 * k + 0] += hl * ((w << 24) >> 24);
                acc[4 * k + 1] += hl * ((w << 16) >> 24);
                acc[4 * k + 2] += hl * ((w << 8) >> 24);
                acc[4 * k + 3] += hl * (w >> 24);
            }
        }
    }

    // wave butterfly reduce -> LDS per-wave row -> thread f sums 4 rows ->
    // one non-atomic global partial row per block.
    const int lane = threadIdx.x & 63;
    const int wv = threadIdx.x >> 6;
#pragma unroll
    for (int f = 0; f < NFEAT; ++f) {
        int v = acc[f];
#pragma unroll
        for (int o = 32; o > 0; o >>= 1) v += __shfl_xor(v, o, 64);
        if (lane == 0) wsum[wv][f] = v;
    }
    __syncthreads();
    if (threadIdx.x < NFEAT) {
        int f = threadIdx.x;
        partial[blockIdx.x * NFEAT + f] = wsum[0][f] + wsum[1][f] + wsum[2][f] + wsum[3][f];
    }
}

// ---------------------------------------------------------------------------
// Kernel 2: finalize. Block f (of 20) sums partial[b][f] over nb blocks,
// then quantizes exactly: mean*4 = S / 2^20; RNE rint == jnp.round.
// ---------------------------------------------------------------------------
__global__ __launch_bounds__(64) void finalize_k(const int* __restrict__ partial,
                                                 float* __restrict__ out, int nb) {
    const int f = blockIdx.x;
    const int lane = threadIdx.x;
    int s = 0;
    for (int b = lane; b < nb; b += 64) s += partial[b * NFEAT + f];
#pragma unroll
    for (int o = 32; o > 0; o >>= 1) s += __shfl_xor(s, o, 64);
    if (lane == 0) {
        double m4 = (double)s * (1.0 / 1048576.0);
        double r = rint(m4);
        float v = (float)(r * 0.25);
        v = fminf(fmaxf(v, -32.0f), 31.75f);
        out[f] = v;
    }
}

extern "C" void kernel_launch(void* const* d_in, const int* in_sizes, int n_in,
                              void* d_out, int out_size, void* d_ws, size_t ws_size,
                              hipStream_t stream) {
    const float* xin = (const float*)d_in[0];
    const float* xs = (const float*)d_in[1];
    const int* msb = (const int*)d_in[2];
    const int* lsb = (const int*)d_in[3];
    float* out = (float*)d_out;

    // workspace layout: compact tables (2 x 96 KiB), then per-block partials
    int* cm = (int*)d_ws;
    int* cl = (int*)((char*)d_ws + 98304);
    int* partial = (int*)((char*)d_ws + 2 * 98304);  // up to 2048*20*4 = 160 KiB

    // 2048 blocks = 8 blocks/CU (the packed-hist headroom); guard on ws.
    const int mb = (ws_size >= (size_t)(2 * 98304) + 2048u * NFEAT * 4u) ? 2048 : 1024;

    compact_k<<<96, 256, 0, stream>>>(msb, lsb, cm, cl);
    feat_main<<<mb, 256, 0, stream>>>(xin, xs, cm, cl, partial);
    finalize_k<<<NFEAT, 64, 0, stream>>>(partial, out, mb);
}

// Round 6
// 155.887 us; speedup vs baseline: 1.0892x; 1.0892x over previous
//
#include <hip/hip_runtime.h>

// FeatLUT: out[f] = quantize( mean_p( msb[idx_m(p)][f] + lsb[idx_l(p)][f] ) )
// idx = 16*(289*c0 + 17*c1 + c2)  -> only 17^3 = 4913 distinct rows used.
// Strategy: per-block LDS histogram of the 4913 small indices, per-block dot
// against compacted tables -> NON-ATOMIC per-block partials, tree-reduce.
//
// Session mines (do not re-trip):
//  - 40960 same-cacheline global atomics serialized = 417us (orig session).
//  - __launch_bounds__ min-waves squeezes VGPR (52->28), serializes load
//    bundles: VALUBusy 6%, 3x slower (R2).
//  - Fused last-block finalize with __threadfence(): agent-scope fence on
//    8-XCD gfx950 = bulk L2 writeback/invalidate per block -> nukes L2 under
//    concurrent streamers; slow even with warm L3 (R2/R3/R4, 3-5x).
//  - Grid 2048 (R6): occupancy 37->70% but 51->63us. Phase B (hist zero +
//    4913-bin scan + table reads) is PER-BLOCK fixed cost; it scales with
//    grid and eats the phase-A gain. Keep grid at 1024.
//
// R7 single change vs R5(157us, feat_main 51us): phase A unrolled 2x with
// all 12 float4 loads hoisted -> 192B/wave in flight at unchanged block
// count (in-flight bytes of R6 without its phase-B doubling).

#define NBINS 4913            // 17^3
#define NPIX  (2048 * 2048)   // 4194304
#define G4    (NPIX / 4)      // 1048576 float4 groups per channel plane
#define NFEAT 20
#define MAIN_BLOCKS 1024      // 4 blocks/CU; G4/(1024*256) = 4 iters = 2 unrolled

// ---------------------------------------------------------------------------
// Kernel 0: compact the used LUT rows (row 16*j, j in [0,4913)) into dense
// 20-byte rows stored as 5 dwords each. Handles both harness layouts for the
// int8 tables: (a) raw int8 bytes, (b) widened to int32. Detection: random
// packed bytes essentially never stay in [-32,32) 64x in a row.
// ---------------------------------------------------------------------------
__global__ __launch_bounds__(256) void compact_k(const int* __restrict__ msb,
                                                 const int* __restrict__ lsb,
                                                 int* __restrict__ cm,
                                                 int* __restrict__ cl) {
    int ok = 1;
    for (int i = 0; i < 64; ++i) {
        int v = msb[i];
        ok &= (v >= -32 && v < 32);
    }
    const bool is_int32 = (ok != 0);

    const int total = NBINS * 5;  // dwords per compact table
    int t = blockIdx.x * 256 + threadIdx.x;
    const int stride = gridDim.x * 256;
    for (; t < total; t += stride) {
        int j = t / 5;
        int k = t - j * 5;
        int wm, wl;
        if (is_int32) {
            // source: int per element; row 16j starts at element 16j*20 = 320j
            const int* rm = msb + j * 320 + k * 4;
            const int* rl = lsb + j * 320 + k * 4;
            unsigned um = (unsigned)(rm[0] & 0xff) | ((unsigned)(rm[1] & 0xff) << 8) |
                          ((unsigned)(rm[2] & 0xff) << 16) | ((unsigned)(rm[3] & 0xff) << 24);
            unsigned ul = (unsigned)(rl[0] & 0xff) | ((unsigned)(rl[1] & 0xff) << 8) |
                          ((unsigned)(rl[2] & 0xff) << 16) | ((unsigned)(rl[3] & 0xff) << 24);
            wm = (int)um;
            wl = (int)ul;
        } else {
            // source: raw int8; row 16j at byte 320j -> dword 80j, 5 dwords/row
            wm = msb[j * 80 + k];
            wl = lsb[j * 80 + k];
        }
        cm[t] = wm;
        cl[t] = wl;
    }
}

#define IDX4(d, v0, v1, v2)                                      \
    int d##0 = (int)fmaf(v0.x, 289.0f, fmaf(v1.x, 17.0f, v2.x)); \
    int d##1 = (int)fmaf(v0.y, 289.0f, fmaf(v1.y, 17.0f, v2.y)); \
    int d##2 = (int)fmaf(v0.z, 289.0f, fmaf(v1.z, 17.0f, v2.z)); \
    int d##3 = (int)fmaf(v0.w, 289.0f, fmaf(v1.w, 17.0f, v2.w));

// ---------------------------------------------------------------------------
// Kernel 1: main. MAIN_BLOCKS x 256 threads.
//  - packed LDS histogram (4913 ints, msb lo16 / lsb hi16; per-block count
//    per table = 4096 < 2^16, no cross-field carry)
//  - phase A: 2 unrolled grid-stride passes, 12 float4 loads hoisted per
//    pass (192B/wave in flight) -- the latency-hiding lever at fixed grid
//  - per-block dot against compact tables, wave shuffle reduce, LDS combine,
//    one NON-ATOMIC 20-int partial row per block.
// ---------------------------------------------------------------------------
__global__ __launch_bounds__(256) void feat_main(const float* __restrict__ xin,
                                                 const float* __restrict__ xs,
                                                 const int* __restrict__ cm,
                                                 const int* __restrict__ cl,
                                                 int* __restrict__ partial) {
    __shared__ int hist[NBINS];   // 19652 B
    __shared__ int wsum[4][NFEAT];
    for (int i = threadIdx.x; i < NBINS; i += 256) hist[i] = 0;
    __syncthreads();

    const float4* a = (const float4*)xin;
    const float4* b = (const float4*)xs;
    const int nt = MAIN_BLOCKS * 256;           // 262144; G4/nt = 4 iters
    int g = blockIdx.x * 256 + threadIdx.x;
#pragma unroll
    for (int it = 0; it < 2; ++it) {
        const int h0 = g, h1 = g + nt;
        // 12 loads issued before any use: 192 B/wave in flight
        float4 a0 = a[h0], a1 = a[h0 + G4], a2 = a[h0 + 2 * G4];
        float4 b0 = b[h0], b1 = b[h0 + G4], b2 = b[h0 + 2 * G4];
        float4 c0 = a[h1], c1 = a[h1 + G4], c2 = a[h1 + 2 * G4];
        float4 d0 = b[h1], d1 = b[h1 + G4], d2 = b[h1 + 2 * G4];

        IDX4(m, a0, a1, a2)
        IDX4(s, b0, b1, b2)
        atomicAdd(&hist[m0], 1);
        atomicAdd(&hist[m1], 1);
        atomicAdd(&hist[m2], 1);
        atomicAdd(&hist[m3], 1);
        atomicAdd(&hist[s0], 1 << 16);
        atomicAdd(&hist[s1], 1 << 16);
        atomicAdd(&hist[s2], 1 << 16);
        atomicAdd(&hist[s3], 1 << 16);

        IDX4(n, c0, c1, c2)
        IDX4(t, d0, d1, d2)
        atomicAdd(&hist[n0], 1);
        atomicAdd(&hist[n1], 1);
        atomicAdd(&hist[n2], 1);
        atomicAdd(&hist[n3], 1);
        atomicAdd(&hist[t0], 1 << 16);
        atomicAdd(&hist[t1], 1 << 16);
        atomicAdd(&hist[t2], 1 << 16);
        atomicAdd(&hist[t3], 1 << 16);

        g += 2 * nt;
    }
    __syncthreads();

    // per-block dot product: acc[f] += hm[j]*msb_row[j][f] + hl[j]*lsb_row[j][f]
    int acc[NFEAT];
#pragma unroll
    for (int f = 0; f < NFEAT; ++f) acc[f] = 0;

    for (int j = threadIdx.x; j < NBINS; j += 256) {
        int h = hist[j];
        int hm = h & 0xffff;
        int hl = (int)((unsigned)h >> 16);
        if (hm) {
            const int* r = cm + j * 5;
#pragma unroll
            for (int k = 0; k < 5; ++k) {
                int w = r[k];
                acc[4 * k + 0] += hm * ((w << 24) >> 24);
                acc[4 * k + 1] += hm * ((w << 16) >> 24);
                acc[4 * k + 2] += hm * ((w << 8) >> 24);
                acc[4 * k + 3] += hm * (w >> 24);
            }
        }
        if (hl) {
            const int* r = cl + j * 5;
#pragma unroll
            for (int k = 0; k < 5; ++k) {
                int w = r[k];
                acc[4 * k + 0] += hl * ((w << 24) >> 24);
                acc[4 * k + 1] += hl * ((w << 16) >> 24);
                acc[4 * k + 2] += hl * ((w << 8) >> 24);
                acc[4 * k + 3] += hl * (w >> 24);
            }
        }
    }

    // wave butterfly reduce -> LDS per-wave row -> thread f sums 4 rows ->
    // one non-atomic global partial row per block.
    const int lane = threadIdx.x & 63;
    const int wv = threadIdx.x >> 6;
#pragma unroll
    for (int f = 0; f < NFEAT; ++f) {
        int v = acc[f];
#pragma unroll
        for (int o = 32; o > 0; o >>= 1) v += __shfl_xor(v, o, 64);
        if (lane == 0) wsum[wv][f] = v;
    }
    __syncthreads();
    if (threadIdx.x < NFEAT) {
        int f = threadIdx.x;
        partial[blockIdx.x * NFEAT + f] = wsum[0][f] + wsum[1][f] + wsum[2][f] + wsum[3][f];
    }
}

// ---------------------------------------------------------------------------
// Kernel 2: finalize. Block f (of 20) sums partial[b][f] over 1024 blocks,
// then quantizes exactly: mean*4 = S / 2^20; RNE rint == jnp.round.
// ---------------------------------------------------------------------------
__global__ __launch_bounds__(64) void finalize_k(const int* __restrict__ partial,
                                                 float* __restrict__ out) {
    const int f = blockIdx.x;
    const int lane = threadIdx.x;
    int s = 0;
    for (int b = lane; b < MAIN_BLOCKS; b += 64) s += partial[b * NFEAT + f];
#pragma unroll
    for (int o = 32; o > 0; o >>= 1) s += __shfl_xor(s, o, 64);
    if (lane == 0) {
        double m4 = (double)s * (1.0 / 1048576.0);
        double r = rint(m4);
        float v = (float)(r * 0.25);
        v = fminf(fmaxf(v, -32.0f), 31.75f);
        out[f] = v;
    }
}

extern "C" void kernel_launch(void* const* d_in, const int* in_sizes, int n_in,
                              void* d_out, int out_size, void* d_ws, size_t ws_size,
                              hipStream_t stream) {
    const float* xin = (const float*)d_in[0];
    const float* xs = (const float*)d_in[1];
    const int* msb = (const int*)d_in[2];
    const int* lsb = (const int*)d_in[3];
    float* out = (float*)d_out;

    // workspace layout: compact tables (2 x 96 KiB), then per-block partials
    int* cm = (int*)d_ws;
    int* cl = (int*)((char*)d_ws + 98304);
    int* partial = (int*)((char*)d_ws + 2 * 98304);  // 1024*20*4 = 80 KiB

    compact_k<<<96, 256, 0, stream>>>(msb, lsb, cm, cl);
    feat_main<<<MAIN_BLOCKS, 256, 0, stream>>>(xin, xs, cm, cl, partial);
    finalize_k<<<NFEAT, 64, 0, stream>>>(partial, out);
}

// Round 7
// 155.449 us; speedup vs baseline: 1.0923x; 1.0028x over previous
//
#include <hip/hip_runtime.h>

// FeatLUT: out[f] = quantize( mean_p( msb[idx_m(p)][f] + lsb[idx_l(p)][f] ) )
// idx = 16*(289*c0 + 17*c1 + c2)  -> only 17^3 = 4913 distinct rows used.
// Strategy: per-block LDS histogram of the 4913 small indices, per-block dot
// against compacted tables -> NON-ATOMIC per-block partials, tree-reduce.
//
// Session mines (do not re-trip):
//  - 40960 same-cacheline global atomics serialized = 417us (orig session).
//  - __launch_bounds__ min-waves squeezes VGPR (52->28), serializes load
//    bundles: VALUBusy 6%, 3x slower (R2).
//  - Fused last-block finalize with __threadfence(): agent-scope fence on
//    8-XCD gfx950 = bulk L2 writeback/invalidate per block -> nukes L2 under
//    concurrent streamers; slow even with warm L3 (R2/R3/R4, 3-5x).
//  - Grid 2048 (R6): occupancy 37->70% but 51->63us. Phase B is PER-BLOCK
//    fixed cost; it scales with grid and eats the phase-A gain. Grid = 1024.
//  - Source-level load hoisting (R7): compiler SINKS the loads back to their
//    uses (VGPR stayed 24) -- null result. Pinning needs sched_barrier.
//
// R8 single change vs R7: __builtin_amdgcn_sched_barrier(0) after each
// 12-load bundle. Nothing crosses the barrier -> all 12 global_load_dwordx4
// issue before the first fmaf, forcing ~48 data VGPRs live and 192B/wave
// in flight (vs ~3-4 loads now). Grid cap 16 waves/CU = 4 waves/SIMD ->
// up to 128 VGPR/wave without occupancy loss.

#define NBINS 4913            // 17^3
#define NPIX  (2048 * 2048)   // 4194304
#define G4    (NPIX / 4)      // 1048576 float4 groups per channel plane
#define NFEAT 20
#define MAIN_BLOCKS 1024      // 4 blocks/CU; G4/(1024*256) = 4 iters = 2 unrolled

// ---------------------------------------------------------------------------
// Kernel 0: compact the used LUT rows (row 16*j, j in [0,4913)) into dense
// 20-byte rows stored as 5 dwords each. Handles both harness layouts for the
// int8 tables: (a) raw int8 bytes, (b) widened to int32. Detection: random
// packed bytes essentially never stay in [-32,32) 64x in a row.
// ---------------------------------------------------------------------------
__global__ __launch_bounds__(256) void compact_k(const int* __restrict__ msb,
                                                 const int* __restrict__ lsb,
                                                 int* __restrict__ cm,
                                                 int* __restrict__ cl) {
    int ok = 1;
    for (int i = 0; i < 64; ++i) {
        int v = msb[i];
        ok &= (v >= -32 && v < 32);
    }
    const bool is_int32 = (ok != 0);

    const int total = NBINS * 5;  // dwords per compact table
    int t = blockIdx.x * 256 + threadIdx.x;
    const int stride = gridDim.x * 256;
    for (; t < total; t += stride) {
        int j = t / 5;
        int k = t - j * 5;
        int wm, wl;
        if (is_int32) {
            // source: int per element; row 16j starts at element 16j*20 = 320j
            const int* rm = msb + j * 320 + k * 4;
            const int* rl = lsb + j * 320 + k * 4;
            unsigned um = (unsigned)(rm[0] & 0xff) | ((unsigned)(rm[1] & 0xff) << 8) |
                          ((unsigned)(rm[2] & 0xff) << 16) | ((unsigned)(rm[3] & 0xff) << 24);
            unsigned ul = (unsigned)(rl[0] & 0xff) | ((unsigned)(rl[1] & 0xff) << 8) |
                          ((unsigned)(rl[2] & 0xff) << 16) | ((unsigned)(rl[3] & 0xff) << 24);
            wm = (int)um;
            wl = (int)ul;
        } else {
            // source: raw int8; row 16j at byte 320j -> dword 80j, 5 dwords/row
            wm = msb[j * 80 + k];
            wl = lsb[j * 80 + k];
        }
        cm[t] = wm;
        cl[t] = wl;
    }
}

#define IDX4(d, v0, v1, v2)                                      \
    int d##0 = (int)fmaf(v0.x, 289.0f, fmaf(v1.x, 17.0f, v2.x)); \
    int d##1 = (int)fmaf(v0.y, 289.0f, fmaf(v1.y, 17.0f, v2.y)); \
    int d##2 = (int)fmaf(v0.z, 289.0f, fmaf(v1.z, 17.0f, v2.z)); \
    int d##3 = (int)fmaf(v0.w, 289.0f, fmaf(v1.w, 17.0f, v2.w));

// ---------------------------------------------------------------------------
// Kernel 1: main. MAIN_BLOCKS x 256 threads.
//  - packed LDS histogram (4913 ints, msb lo16 / lsb hi16; per-block count
//    per table = 4096 < 2^16, no cross-field carry)
//  - phase A: 2 unrolled passes; 12 float4 loads + sched_barrier(0) pin ->
//    all 12 loads in flight before any consumer (192B/wave MLP)
//  - per-block dot against compact tables, wave shuffle reduce, LDS combine,
//    one NON-ATOMIC 20-int partial row per block.
// ---------------------------------------------------------------------------
__global__ __launch_bounds__(256) void feat_main(const float* __restrict__ xin,
                                                 const float* __restrict__ xs,
                                                 const int* __restrict__ cm,
                                                 const int* __restrict__ cl,
                                                 int* __restrict__ partial) {
    __shared__ int hist[NBINS];   // 19652 B
    __shared__ int wsum[4][NFEAT];
    for (int i = threadIdx.x; i < NBINS; i += 256) hist[i] = 0;
    __syncthreads();

    const float4* a = (const float4*)xin;
    const float4* b = (const float4*)xs;
    const int nt = MAIN_BLOCKS * 256;           // 262144; G4/nt = 4 iters
    int g = blockIdx.x * 256 + threadIdx.x;
#pragma unroll
    for (int it = 0; it < 2; ++it) {
        const int h0 = g, h1 = g + nt;
        // 12 loads, then a hard scheduling fence: nothing may cross, so all
        // 12 global_load_dwordx4 issue before the first use (R7: without
        // this the compiler sinks them and MLP collapses to ~3-4).
        float4 a0 = a[h0], a1 = a[h0 + G4], a2 = a[h0 + 2 * G4];
        float4 b0 = b[h0], b1 = b[h0 + G4], b2 = b[h0 + 2 * G4];
        float4 c0 = a[h1], c1 = a[h1 + G4], c2 = a[h1 + 2 * G4];
        float4 d0 = b[h1], d1 = b[h1 + G4], d2 = b[h1 + 2 * G4];
        __builtin_amdgcn_sched_barrier(0);

        IDX4(m, a0, a1, a2)
        IDX4(s, b0, b1, b2)
        atomicAdd(&hist[m0], 1);
        atomicAdd(&hist[m1], 1);
        atomicAdd(&hist[m2], 1);
        atomicAdd(&hist[m3], 1);
        atomicAdd(&hist[s0], 1 << 16);
        atomicAdd(&hist[s1], 1 << 16);
        atomicAdd(&hist[s2], 1 << 16);
        atomicAdd(&hist[s3], 1 << 16);

        IDX4(n, c0, c1, c2)
        IDX4(t, d0, d1, d2)
        atomicAdd(&hist[n0], 1);
        atomicAdd(&hist[n1], 1);
        atomicAdd(&hist[n2], 1);
        atomicAdd(&hist[n3], 1);
        atomicAdd(&hist[t0], 1 << 16);
        atomicAdd(&hist[t1], 1 << 16);
        atomicAdd(&hist[t2], 1 << 16);
        atomicAdd(&hist[t3], 1 << 16);

        g += 2 * nt;
    }
    __syncthreads();

    // per-block dot product: acc[f] += hm[j]*msb_row[j][f] + hl[j]*lsb_row[j][f]
    int acc[NFEAT];
#pragma unroll
    for (int f = 0; f < NFEAT; ++f) acc[f] = 0;

    for (int j = threadIdx.x; j < NBINS; j += 256) {
        int h = hist[j];
        int hm = h & 0xffff;
        int hl = (int)((unsigned)h >> 16);
        if (hm) {
            const int* r = cm + j * 5;
#pragma unroll
            for (int k = 0; k < 5; ++k) {
                int w = r[k];
                acc[4 * k + 0] += hm * ((w << 24) >> 24);
                acc[4 * k + 1] += hm * ((w << 16) >> 24);
                acc[4 * k + 2] += hm * ((w << 8) >> 24);
                acc[4 * k + 3] += hm * (w >> 24);
            }
        }
        if (hl) {
            const int* r = cl + j * 5;
#pragma unroll
            for (int k = 0; k < 5; ++k) {
                int w = r[k];
                acc[4 * k + 0] += hl * ((w << 24) >> 24);
                acc[4 * k + 1] += hl * ((w << 16) >> 24);
                acc[4 * k + 2] += hl * ((w << 8) >> 24);
                acc[4 * k + 3] += hl * (w >> 24);
            }
        }
    }

    // wave butterfly reduce -> LDS per-wave row -> thread f sums 4 rows ->
    // one non-atomic global partial row per block.
    const int lane = threadIdx.x & 63;
    const int wv = threadIdx.x >> 6;
#pragma unroll
    for (int f = 0; f < NFEAT; ++f) {
        int v = acc[f];
#pragma unroll
        for (int o = 32; o > 0; o >>= 1) v += __shfl_xor(v, o, 64);
        if (lane == 0) wsum[wv][f] = v;
    }
    __syncthreads();
    if (threadIdx.x < NFEAT) {
        int f = threadIdx.x;
        partial[blockIdx.x * NFEAT + f] = wsum[0][f] + wsum[1][f] + wsum[2][f] + wsum[3][f];
    }
}

// ---------------------------------------------------------------------------
// Kernel 2: finalize. Block f (of 20) sums partial[b][f] over 1024 blocks,
// then quantizes exactly: mean*4 = S / 2^20; RNE rint == jnp.round.
// ---------------------------------------------------------------------------
__global__ __launch_bounds__(64) void finalize_k(const int* __restrict__ partial,
                                                 float* __restrict__ out) {
    const int f = blockIdx.x;
    const int lane = threadIdx.x;
    int s = 0;
    for (int b = lane; b < MAIN_BLOCKS; b += 64) s += partial[b * NFEAT + f];
#pragma unroll
    for (int o = 32; o > 0; o >>= 1) s += __shfl_xor(s, o, 64);
    if (lane == 0) {
        double m4 = (double)s * (1.0 / 1048576.0);
        double r = rint(m4);
        float v = (float)(r * 0.25);
        v = fminf(fmaxf(v, -32.0f), 31.75f);
        out[f] = v;
    }
}

extern "C" void kernel_launch(void* const* d_in, const int* in_sizes, int n_in,
                              void* d_out, int out_size, void* d_ws, size_t ws_size,
                              hipStream_t stream) {
    const float* xin = (const float*)d_in[0];
    const float* xs = (const float*)d_in[1];
    const int* msb = (const int*)d_in[2];
    const int* lsb = (const int*)d_in[3];
    float* out = (float*)d_out;

    // workspace layout: compact tables (2 x 96 KiB), then per-block partials
    int* cm = (int*)d_ws;
    int* cl = (int*)((char*)d_ws + 98304);
    int* partial = (int*)((char*)d_ws + 2 * 98304);  // 1024*20*4 = 80 KiB

    compact_k<<<96, 256, 0, stream>>>(msb, lsb, cm, cl);
    feat_main<<<MAIN_BLOCKS, 256, 0, stream>>>(xin, xs, cm, cl, partial);
    finalize_k<<<NFEAT, 64, 0, stream>>>(partial, out);
}